// Round 1
// baseline (644.960 us; speedup 1.0000x reference)
//
#include <hip/hip_runtime.h>
#include <hip/hip_bf16.h>

// Sizes (compile-time constants for this problem)
// B=8, DIM=512, H=W=32 (1024 pos), HC=WC=32, NH=8, DH=64, DE=512

// ---------------------------------------------------------------------------
// Kernel A: per-position channel L2 norm -> scale s = sqrt(512)/max(||x||,1e-12)
// grid: 256 blocks = tensor(2) x b(8) x chunk(16 of 64 pos), block 256
// thread = (pos in chunk [0..63], channel-quarter [0..3])
// ---------------------------------------------------------------------------
__global__ __launch_bounds__(256) void norm_kernel(
    const float* __restrict__ x, const float* __restrict__ ctx,
    float* __restrict__ sx, float* __restrict__ sc) {
  int bid = blockIdx.x;
  int tensor = bid >> 7;
  int b = (bid >> 4) & 7;
  int chunk = bid & 15;
  const float* src = tensor ? ctx : x;
  float* dst = tensor ? sc : sx;
  int t = threadIdx.x;
  int posl = t & 63;
  int cq = t >> 6;  // 0..3, 128 channels each
  int pos = (chunk << 6) + posl;
  const float* p = src + ((size_t)(b * 512 + cq * 128)) * 1024 + pos;
  float acc = 0.f;
#pragma unroll 8
  for (int c = 0; c < 128; ++c) {
    float v = p[(size_t)c * 1024];
    acc += v * v;
  }
  __shared__ float red[4][64];
  red[cq][posl] = acc;
  __syncthreads();
  if (t < 64) {
    float sum = red[0][t] + red[1][t] + red[2][t] + red[3][t];
    dst[b * 1024 + (chunk << 6) + t] =
        22.627416997969522f / fmaxf(sqrtf(sum), 1e-12f);
  }
}

// ---------------------------------------------------------------------------
// Kernel B: fused QKV projection GEMM.
//   O[o,pos] = (sum_c W[o,c]*gamma[c]*X[b,c,pos]) * s[b,pos]
// scattered to head layout qh[(b*8+n)*1024 + pos][dh],  o = dh*8 + n
// grid: (pos tiles 16, o tiles 8, b*3+proj 24), block 256
// ---------------------------------------------------------------------------
__global__ __launch_bounds__(256) void qkv_kernel(
    const float* __restrict__ x, const float* __restrict__ ctx,
    const float* __restrict__ gamma,
    const float* __restrict__ wq, const float* __restrict__ wk,
    const float* __restrict__ wv,
    const float* __restrict__ sx, const float* __restrict__ sc,
    float* __restrict__ qh, float* __restrict__ kh, float* __restrict__ vh) {
  int proj = blockIdx.z % 3;
  int b = blockIdx.z / 3;
  const float* X = proj ? ctx : x;
  const float* W = (proj == 0) ? wq : (proj == 1 ? wk : wv);
  const float* S = proj ? sc : sx;
  float* Out = (proj == 0) ? qh : (proj == 1 ? kh : vh);

  int posBase = blockIdx.x << 6;
  int oBase = blockIdx.y << 6;
  int t = threadIdx.x;
  int tx = t & 15, ty = t >> 4;

  __shared__ float As[16][64];  // [k][o]  (gamma folded in)
  __shared__ float Bs[16][64];  // [k][pos]
  float acc[4][4] = {{0.f}};

  int aO = t >> 2;          // 0..63
  int aK = (t & 3) << 2;    // 0,4,8,12
  int bK = t >> 4;          // 0..15
  int bC = (t & 15) << 2;   // 0..60

  for (int k0 = 0; k0 < 512; k0 += 16) {
    float4 w4 = *(const float4*)&W[(size_t)(oBase + aO) * 512 + k0 + aK];
    float4 g4 = *(const float4*)&gamma[k0 + aK];
    float4 x4 = *(const float4*)&X[((size_t)(b * 512 + k0 + bK)) * 1024 +
                                   posBase + bC];
    __syncthreads();
    As[aK + 0][aO] = w4.x * g4.x;
    As[aK + 1][aO] = w4.y * g4.y;
    As[aK + 2][aO] = w4.z * g4.z;
    As[aK + 3][aO] = w4.w * g4.w;
    *(float4*)&Bs[bK][bC] = x4;
    __syncthreads();
#pragma unroll
    for (int kk = 0; kk < 16; ++kk) {
      float4 av = *(const float4*)&As[kk][ty << 2];
      float4 bv = *(const float4*)&Bs[kk][tx << 2];
      acc[0][0] += av.x * bv.x; acc[0][1] += av.x * bv.y;
      acc[0][2] += av.x * bv.z; acc[0][3] += av.x * bv.w;
      acc[1][0] += av.y * bv.x; acc[1][1] += av.y * bv.y;
      acc[1][2] += av.y * bv.z; acc[1][3] += av.y * bv.w;
      acc[2][0] += av.z * bv.x; acc[2][1] += av.z * bv.y;
      acc[2][2] += av.z * bv.z; acc[2][3] += av.z * bv.w;
      acc[3][0] += av.w * bv.x; acc[3][1] += av.w * bv.y;
      acc[3][2] += av.w * bv.z; acc[3][3] += av.w * bv.w;
    }
  }

  float4 sv4 = *(const float4*)&S[b * 1024 + posBase + (tx << 2)];
  float sarr[4] = {sv4.x, sv4.y, sv4.z, sv4.w};
#pragma unroll
  for (int i = 0; i < 4; ++i) {
    int o = oBase + (ty << 2) + i;
    int dh = o >> 3, n = o & 7;
    size_t base =
        ((size_t)((b * 8 + n) * 1024) + posBase + (tx << 2)) * 64 + dh;
#pragma unroll
    for (int j = 0; j < 4; ++j) {
      Out[base + (size_t)j * 64] = acc[i][j] * sarr[j];
    }
  }
}

// ---------------------------------------------------------------------------
// Kernel C: attention for one (b,head): O = (softmax(Q K^T / 8)+1e-8) V + 1e-8
// One thread per q-row (64 regs q, 64 regs O). No max-subtraction (logits
// bounded ~|1.3|, exp exact in fp32). K/V tiles (64x64) staged in LDS.
// grid: 256 blocks = bh(64) x mchunk(4 of 256 rows), block 256
// Output written in merged layout am[b][dh*8+n][pos].
// ---------------------------------------------------------------------------
__global__ __launch_bounds__(256) void attn_kernel(
    const float* __restrict__ qh, const float* __restrict__ kh,
    const float* __restrict__ vh, float* __restrict__ am) {
  int blk = blockIdx.x;
  int bh = blk >> 2;
  int t = threadIdx.x;
  int m = ((blk & 3) << 8) + t;

  __shared__ float Ks[64][64];
  __shared__ float Vs[64][64];

  float q[64], O[64];
  const float* qp = qh + ((size_t)bh * 1024 + m) * 64;
#pragma unroll
  for (int d = 0; d < 64; d += 4) {
    float4 v = *(const float4*)&qp[d];
    q[d] = v.x; q[d + 1] = v.y; q[d + 2] = v.z; q[d + 3] = v.w;
  }
#pragma unroll
  for (int d = 0; d < 64; ++d) O[d] = 0.f;
  float l = 0.f;

  for (int kt = 0; kt < 16; ++kt) {
    __syncthreads();
    const float* kb = kh + ((size_t)bh * 1024 + kt * 64) * 64;
    const float* vb = vh + ((size_t)bh * 1024 + kt * 64) * 64;
#pragma unroll
    for (int i = 0; i < 4; ++i) {
      int lin = t + (i << 8);           // float4 index 0..1023
      int r = lin >> 4, c4 = (lin & 15) << 2;
      *(float4*)&Ks[r][c4] = *(const float4*)&kb[(size_t)r * 64 + c4];
      *(float4*)&Vs[r][c4] = *(const float4*)&vb[(size_t)r * 64 + c4];
    }
    __syncthreads();
    for (int j = 0; j < 64; ++j) {
      float s0 = 0.f, s1 = 0.f, s2 = 0.f, s3 = 0.f;
#pragma unroll
      for (int d = 0; d < 64; d += 4) {
        float4 kv = *(const float4*)&Ks[j][d];
        s0 += q[d] * kv.x; s1 += q[d + 1] * kv.y;
        s2 += q[d + 2] * kv.z; s3 += q[d + 3] * kv.w;
      }
      float p = __expf((s0 + s1 + s2 + s3) * 0.125f);
      l += p;
#pragma unroll
      for (int d = 0; d < 64; d += 4) {
        float4 vv = *(const float4*)&Vs[j][d];
        O[d] += p * vv.x; O[d + 1] += p * vv.y;
        O[d + 2] += p * vv.z; O[d + 3] += p * vv.w;
      }
    }
  }

  float inv = 1.0f / l;
  int b = bh >> 3, n = bh & 7;
  float* ob = am + (size_t)(b * 512 + n) * 1024 + m;
#pragma unroll
  for (int d = 0; d < 64; ++d) {
    ob[(size_t)d * 8192] = O[d] * inv + 1e-8f;
  }
}

// ---------------------------------------------------------------------------
// Kernel D: output projection out[b,o,pos] = sum_c w_proj[o,c] * am[b,c,pos]
// grid: (pos tiles 16, o tiles 8, b 8), block 256
// ---------------------------------------------------------------------------
__global__ __launch_bounds__(256) void proj_kernel(
    const float* __restrict__ am, const float* __restrict__ wp,
    float* __restrict__ out) {
  int b = blockIdx.z;
  int posBase = blockIdx.x << 6;
  int oBase = blockIdx.y << 6;
  int t = threadIdx.x;
  int tx = t & 15, ty = t >> 4;

  __shared__ float As[16][64];
  __shared__ float Bs[16][64];
  float acc[4][4] = {{0.f}};

  int aO = t >> 2;
  int aK = (t & 3) << 2;
  int bK = t >> 4;
  int bC = (t & 15) << 2;

  for (int k0 = 0; k0 < 512; k0 += 16) {
    float4 w4 = *(const float4*)&wp[(size_t)(oBase + aO) * 512 + k0 + aK];
    float4 x4 = *(const float4*)&am[((size_t)(b * 512 + k0 + bK)) * 1024 +
                                    posBase + bC];
    __syncthreads();
    As[aK + 0][aO] = w4.x;
    As[aK + 1][aO] = w4.y;
    As[aK + 2][aO] = w4.z;
    As[aK + 3][aO] = w4.w;
    *(float4*)&Bs[bK][bC] = x4;
    __syncthreads();
#pragma unroll
    for (int kk = 0; kk < 16; ++kk) {
      float4 av = *(const float4*)&As[kk][ty << 2];
      float4 bv = *(const float4*)&Bs[kk][tx << 2];
      acc[0][0] += av.x * bv.x; acc[0][1] += av.x * bv.y;
      acc[0][2] += av.x * bv.z; acc[0][3] += av.x * bv.w;
      acc[1][0] += av.y * bv.x; acc[1][1] += av.y * bv.y;
      acc[1][2] += av.y * bv.z; acc[1][3] += av.y * bv.w;
      acc[2][0] += av.z * bv.x; acc[2][1] += av.z * bv.y;
      acc[2][2] += av.z * bv.z; acc[2][3] += av.z * bv.w;
      acc[3][0] += av.w * bv.x; acc[3][1] += av.w * bv.y;
      acc[3][2] += av.w * bv.z; acc[3][3] += av.w * bv.w;
    }
  }

#pragma unroll
  for (int i = 0; i < 4; ++i) {
    int o = oBase + (ty << 2) + i;
    float4 res = make_float4(acc[i][0], acc[i][1], acc[i][2], acc[i][3]);
    *(float4*)&out[((size_t)(b * 512 + o)) * 1024 + posBase + (tx << 2)] = res;
  }
}

// ---------------------------------------------------------------------------
extern "C" void kernel_launch(void* const* d_in, const int* in_sizes, int n_in,
                              void* d_out, int out_size, void* d_ws,
                              size_t ws_size, hipStream_t stream) {
  const float* x = (const float*)d_in[0];
  const float* ctx = (const float*)d_in[1];
  const float* gamma = (const float*)d_in[2];
  const float* wq = (const float*)d_in[3];
  const float* wk = (const float*)d_in[4];
  const float* wv = (const float*)d_in[5];
  const float* wp = (const float*)d_in[6];
  float* out = (float*)d_out;

  float* ws = (float*)d_ws;
  float* sx = ws;                    // 8192
  float* sc = ws + 8192;             // 8192
  float* qh = ws + 16384;            // 4194304 (B*NH,1024,64)
  float* kh = qh + 4194304;          // 4194304
  float* vh = kh + 4194304;          // 4194304
  float* am = vh + 4194304;          // 4194304 (B,512,1024) merged attn

  norm_kernel<<<256, 256, 0, stream>>>(x, ctx, sx, sc);
  qkv_kernel<<<dim3(16, 8, 24), 256, 0, stream>>>(x, ctx, gamma, wq, wk, wv,
                                                  sx, sc, qh, kh, vh);
  attn_kernel<<<256, 256, 0, stream>>>(qh, kh, vh, am);
  proj_kernel<<<dim3(16, 8, 8), 256, 0, stream>>>(am, wp, out);
}

// Round 2
// 288.176 us; speedup vs baseline: 2.2381x; 2.2381x over previous
//
#include <hip/hip_runtime.h>
#include <hip/hip_bf16.h>

// B=8, DIM=512, H=W=32 (1024 pos), NH=8, DH=64, DE=512

typedef __attribute__((ext_vector_type(8))) short short8v;
typedef __attribute__((ext_vector_type(4))) float float4v;

__device__ inline ushort f2bf(float f) {
  unsigned u = __float_as_uint(f);
  return (ushort)((u + 0x7fffu + ((u >> 16) & 1u)) >> 16);
}

__device__ inline void stage16(const void* g, void* l) {
  __builtin_amdgcn_global_load_lds(
      (const __attribute__((address_space(1))) unsigned*)g,
      (__attribute__((address_space(3))) unsigned*)l, 16, 0, 0);
}

// ---------------------------------------------------------------------------
// Kernel A: per-position channel L2 norm -> s = sqrt(512)/max(||x||,1e-12)
// ---------------------------------------------------------------------------
__global__ __launch_bounds__(256) void norm_kernel(
    const float* __restrict__ x, const float* __restrict__ ctx,
    float* __restrict__ sx, float* __restrict__ sc) {
  int bid = blockIdx.x;
  int tensor = bid >> 7;
  int b = (bid >> 4) & 7;
  int chunk = bid & 15;
  const float* src = tensor ? ctx : x;
  float* dst = tensor ? sc : sx;
  int t = threadIdx.x;
  int posl = t & 63;
  int cq = t >> 6;
  int pos = (chunk << 6) + posl;
  const float* p = src + ((size_t)(b * 512 + cq * 128)) * 1024 + pos;
  float acc = 0.f;
#pragma unroll 8
  for (int c = 0; c < 128; ++c) {
    float v = p[(size_t)c * 1024];
    acc += v * v;
  }
  __shared__ float red[4][64];
  red[cq][posl] = acc;
  __syncthreads();
  if (t < 64) {
    float sum = red[0][t] + red[1][t] + red[2][t] + red[3][t];
    dst[b * 1024 + (chunk << 6) + t] =
        22.627416997969522f / fmaxf(sqrtf(sum), 1e-12f);
  }
}

// ---------------------------------------------------------------------------
// Kernel B: fused QKV projection GEMM (fp32 compute, bf16 output).
// q,k layout: [bh][pos][dh] bf16 ; v layout TRANSPOSED: [bh][dh][pos] bf16
// ---------------------------------------------------------------------------
__global__ __launch_bounds__(256) void qkv_kernel(
    const float* __restrict__ x, const float* __restrict__ ctx,
    const float* __restrict__ gamma,
    const float* __restrict__ wq, const float* __restrict__ wk,
    const float* __restrict__ wv,
    const float* __restrict__ sx, const float* __restrict__ sc,
    ushort* __restrict__ qh, ushort* __restrict__ kh,
    ushort* __restrict__ vt) {
  int proj = blockIdx.z % 3;
  int b = blockIdx.z / 3;
  const float* X = proj ? ctx : x;
  const float* W = (proj == 0) ? wq : (proj == 1 ? wk : wv);
  const float* S = proj ? sc : sx;
  ushort* Out = (proj == 0) ? qh : (proj == 1 ? kh : vt);

  int posBase = blockIdx.x << 6;
  int oBase = blockIdx.y << 6;
  int t = threadIdx.x;
  int tx = t & 15, ty = t >> 4;

  __shared__ float As[16][64];
  __shared__ float Bs[16][64];
  float acc[4][4] = {{0.f}};

  int aO = t >> 2;
  int aK = (t & 3) << 2;
  int bK = t >> 4;
  int bC = (t & 15) << 2;

  for (int k0 = 0; k0 < 512; k0 += 16) {
    float4 w4 = *(const float4*)&W[(size_t)(oBase + aO) * 512 + k0 + aK];
    float4 g4 = *(const float4*)&gamma[k0 + aK];
    float4 x4 = *(const float4*)&X[((size_t)(b * 512 + k0 + bK)) * 1024 +
                                   posBase + bC];
    __syncthreads();
    As[aK + 0][aO] = w4.x * g4.x;
    As[aK + 1][aO] = w4.y * g4.y;
    As[aK + 2][aO] = w4.z * g4.z;
    As[aK + 3][aO] = w4.w * g4.w;
    *(float4*)&Bs[bK][bC] = x4;
    __syncthreads();
#pragma unroll
    for (int kk = 0; kk < 16; ++kk) {
      float4 av = *(const float4*)&As[kk][ty << 2];
      float4 bv = *(const float4*)&Bs[kk][tx << 2];
      acc[0][0] += av.x * bv.x; acc[0][1] += av.x * bv.y;
      acc[0][2] += av.x * bv.z; acc[0][3] += av.x * bv.w;
      acc[1][0] += av.y * bv.x; acc[1][1] += av.y * bv.y;
      acc[1][2] += av.y * bv.z; acc[1][3] += av.y * bv.w;
      acc[2][0] += av.z * bv.x; acc[2][1] += av.z * bv.y;
      acc[2][2] += av.z * bv.z; acc[2][3] += av.z * bv.w;
      acc[3][0] += av.w * bv.x; acc[3][1] += av.w * bv.y;
      acc[3][2] += av.w * bv.z; acc[3][3] += av.w * bv.w;
    }
  }

  float4 sv4 = *(const float4*)&S[b * 1024 + posBase + (tx << 2)];
  float sarr[4] = {sv4.x, sv4.y, sv4.z, sv4.w};
#pragma unroll
  for (int i = 0; i < 4; ++i) {
    int o = oBase + (ty << 2) + i;
    int dh = o >> 3, n = o & 7;
    if (proj < 2) {
      size_t base =
          ((size_t)((b * 8 + n) * 1024) + posBase + (tx << 2)) * 64 + dh;
#pragma unroll
      for (int j = 0; j < 4; ++j)
        Out[base + (size_t)j * 64] = f2bf(acc[i][j] * sarr[j]);
    } else {
      size_t base =
          ((size_t)((b * 8 + n) * 64 + dh)) * 1024 + posBase + (tx << 2);
#pragma unroll
      for (int j = 0; j < 4; ++j)
        Out[base + j] = f2bf(acc[i][j] * sarr[j]);
    }
  }
}

// ---------------------------------------------------------------------------
// Kernel C: MFMA flash attention per (bh, 256-row M-tile).
// 8 waves x 32 q-rows. KVBLK=64 double-buffered via global_load_lds with
// pre-swizzled source (XOR swizzle byte^=(row&7)<<4 on all LDS tiles).
// Swapped QK^T: S^T = K·Q^T so P-rows are lane-local (row=lane&15).
// Output: am[b][dh*8+n][pos] fp32 (= softmax@V + 1e-8, max-free softmax).
// ---------------------------------------------------------------------------
__global__ __launch_bounds__(512, 2) void attn_kernel(
    const ushort* __restrict__ qh, const ushort* __restrict__ kh,
    const ushort* __restrict__ vt, float* __restrict__ am) {
  __shared__ __align__(16) unsigned char lds[65536];
  // K: [0,16384) two 8KB buffers; V: [16384,32768); P: 32768 + w*4096

  const int bh = blockIdx.y;
  const int mbase = blockIdx.x << 8;
  const int t = threadIdx.x;
  const int w = t >> 6;
  const int lane = t & 63;
  const int g = lane >> 4;
  const int l15 = lane & 15;
  const int swz = (l15 & 7) << 4;

  // Q fragments in registers: qf[qt][chunk], rows mbase+w*32+qt*16+l15
  short8v qf[2][2];
  const size_t qbase = (size_t)bh * 1024 + mbase + w * 32;
#pragma unroll
  for (int qt = 0; qt < 2; ++qt)
#pragma unroll
    for (int c = 0; c < 2; ++c)
      qf[qt][c] =
          *(const short8v*)(qh + (qbase + qt * 16 + l15) * 64 + c * 32 + g * 8);

  float4v o[2][4];
#pragma unroll
  for (int qt = 0; qt < 2; ++qt)
#pragma unroll
    for (int dt = 0; dt < 4; ++dt) o[qt][dt] = (float4v){0.f, 0.f, 0.f, 0.f};
  float rsum[2] = {0.f, 0.f};

  // staging: wave w stages rows w*8+(lane>>3), pre-swizzled source column
  const int srow = (w << 3) + (lane >> 3);
  const int scol = ((lane & 7) ^ (lane >> 3)) << 4;  // bytes
  const unsigned char* kgb =
      (const unsigned char*)(kh + (size_t)bh * 65536) + srow * 128 + scol;
  const unsigned char* vgb =
      (const unsigned char*)(vt + (size_t)bh * 65536) + srow * 2048 + scol;
  unsigned char* Kl = lds;
  unsigned char* Vl = lds + 16384;
  unsigned char* Pl = lds + 32768 + w * 4096;

#define STAGE(buf, kt)                                        \
  do {                                                        \
    stage16(kgb + (size_t)(kt)*8192, Kl + (buf)*8192 + w * 1024); \
    stage16(vgb + (size_t)(kt)*128, Vl + (buf)*8192 + w * 1024);  \
  } while (0)

  STAGE(0, 0);
  __syncthreads();

  for (int kt = 0; kt < 16; ++kt) {
    const int cur = kt & 1;
    if (kt < 15) STAGE(cur ^ 1, kt + 1);

    const unsigned char* Kc = Kl + cur * 8192;
    const unsigned char* Vc = Vl + cur * 8192;

    // S^T = K_tile(64x64) · Q^T(64x32): st[keytile][qt]
    float4v st[4][2];
#pragma unroll
    for (int ktile = 0; ktile < 4; ++ktile) {
      const unsigned char* krow = Kc + (ktile * 16 + l15) * 128;
      short8v kf0 = *(const short8v*)(krow + ((g * 16) ^ swz));
      short8v kf1 = *(const short8v*)(krow + ((64 + g * 16) ^ swz));
#pragma unroll
      for (int qt = 0; qt < 2; ++qt) {
        float4v acc = {0.f, 0.f, 0.f, 0.f};
        acc = __builtin_amdgcn_mfma_f32_16x16x32_bf16(kf0, qf[qt][0], acc, 0, 0, 0);
        acc = __builtin_amdgcn_mfma_f32_16x16x32_bf16(kf1, qf[qt][1], acc, 0, 0, 0);
        st[ktile][qt] = acc;
      }
    }

    // softmax (max-free, logits ~|1.3|) + P write (packed b64, swizzled)
#pragma unroll
    for (int qt = 0; qt < 2; ++qt) {
      unsigned char* prowp = Pl + (qt * 16 + l15) * 128;
#pragma unroll
      for (int ktile = 0; ktile < 4; ++ktile) {
        union { unsigned long long u; ushort s[4]; } pk;
        float4v sv = st[ktile][qt];
#pragma unroll
        for (int r = 0; r < 4; ++r) {
          float p = __expf(sv[r] * 0.125f);
          rsum[qt] += p;
          pk.s[r] = f2bf(p);
        }
        *(unsigned long long*)(prowp + ((ktile * 32 + g * 8) ^ swz)) = pk.u;
      }
    }

    // PV: O(32xq x 64d) += P(32x64) · V(64x64)
    short8v pf[2][2];
#pragma unroll
    for (int qt = 0; qt < 2; ++qt)
#pragma unroll
      for (int c = 0; c < 2; ++c)
        pf[qt][c] = *(const short8v*)(Pl + (qt * 16 + l15) * 128 +
                                      ((c * 64 + g * 16) ^ swz));
#pragma unroll
    for (int dt = 0; dt < 4; ++dt) {
      const unsigned char* vrow = Vc + (dt * 16 + l15) * 128;
      short8v vf0 = *(const short8v*)(vrow + ((g * 16) ^ swz));
      short8v vf1 = *(const short8v*)(vrow + ((64 + g * 16) ^ swz));
#pragma unroll
      for (int qt = 0; qt < 2; ++qt) {
        o[qt][dt] = __builtin_amdgcn_mfma_f32_16x16x32_bf16(pf[qt][0], vf0,
                                                            o[qt][dt], 0, 0, 0);
        o[qt][dt] = __builtin_amdgcn_mfma_f32_16x16x32_bf16(pf[qt][1], vf1,
                                                            o[qt][dt], 0, 0, 0);
      }
    }
    __syncthreads();
  }
#undef STAGE

  // row-sum reduce across the 4 lane-groups, then invert
#pragma unroll
  for (int qt = 0; qt < 2; ++qt) {
    float r = rsum[qt];
    r += __shfl_xor(r, 16, 64);
    r += __shfl_xor(r, 32, 64);
    rsum[qt] = 1.0f / r;
  }

  const int b = bh >> 3, n = bh & 7;
#pragma unroll
  for (int qt = 0; qt < 2; ++qt) {
#pragma unroll
    for (int dt = 0; dt < 4; ++dt) {
      float4v ov = o[qt][dt];
      float vals[4];
#pragma unroll
      for (int r = 0; r < 4; ++r) {
        float inv = __shfl(rsum[qt], (lane & 48) | (g * 4 + r), 64);
        vals[r] = ov[r] * inv + 1e-8f;
      }
      const int d = dt * 16 + l15;
      const int pos = mbase + w * 32 + qt * 16 + g * 4;
      float* op = am + ((size_t)(b * 512 + d * 8 + n)) * 1024 + pos;
      *(float4*)op = make_float4(vals[0], vals[1], vals[2], vals[3]);
    }
  }
}

// ---------------------------------------------------------------------------
// Kernel D: output projection out[b,o,pos] = sum_c w_proj[o,c] * am[b,c,pos]
// ---------------------------------------------------------------------------
__global__ __launch_bounds__(256) void proj_kernel(
    const float* __restrict__ am, const float* __restrict__ wp,
    float* __restrict__ out) {
  int b = blockIdx.z;
  int posBase = blockIdx.x << 6;
  int oBase = blockIdx.y << 6;
  int t = threadIdx.x;
  int tx = t & 15, ty = t >> 4;

  __shared__ float As[16][64];
  __shared__ float Bs[16][64];
  float acc[4][4] = {{0.f}};

  int aO = t >> 2;
  int aK = (t & 3) << 2;
  int bK = t >> 4;
  int bC = (t & 15) << 2;

  for (int k0 = 0; k0 < 512; k0 += 16) {
    float4 w4 = *(const float4*)&wp[(size_t)(oBase + aO) * 512 + k0 + aK];
    float4 x4 = *(const float4*)&am[((size_t)(b * 512 + k0 + bK)) * 1024 +
                                    posBase + bC];
    __syncthreads();
    As[aK + 0][aO] = w4.x;
    As[aK + 1][aO] = w4.y;
    As[aK + 2][aO] = w4.z;
    As[aK + 3][aO] = w4.w;
    *(float4*)&Bs[bK][bC] = x4;
    __syncthreads();
#pragma unroll
    for (int kk = 0; kk < 16; ++kk) {
      float4 av = *(const float4*)&As[kk][ty << 2];
      float4 bv = *(const float4*)&Bs[kk][tx << 2];
      acc[0][0] += av.x * bv.x; acc[0][1] += av.x * bv.y;
      acc[0][2] += av.x * bv.z; acc[0][3] += av.x * bv.w;
      acc[1][0] += av.y * bv.x; acc[1][1] += av.y * bv.y;
      acc[1][2] += av.y * bv.z; acc[1][3] += av.y * bv.w;
      acc[2][0] += av.z * bv.x; acc[2][1] += av.z * bv.y;
      acc[2][2] += av.z * bv.z; acc[2][3] += av.z * bv.w;
      acc[3][0] += av.w * bv.x; acc[3][1] += av.w * bv.y;
      acc[3][2] += av.w * bv.z; acc[3][3] += av.w * bv.w;
    }
  }

#pragma unroll
  for (int i = 0; i < 4; ++i) {
    int o = oBase + (ty << 2) + i;
    float4 res = make_float4(acc[i][0], acc[i][1], acc[i][2], acc[i][3]);
    *(float4*)&out[((size_t)(b * 512 + o)) * 1024 + posBase + (tx << 2)] = res;
  }
}

// ---------------------------------------------------------------------------
extern "C" void kernel_launch(void* const* d_in, const int* in_sizes, int n_in,
                              void* d_out, int out_size, void* d_ws,
                              size_t ws_size, hipStream_t stream) {
  const float* x = (const float*)d_in[0];
  const float* ctx = (const float*)d_in[1];
  const float* gamma = (const float*)d_in[2];
  const float* wq = (const float*)d_in[3];
  const float* wk = (const float*)d_in[4];
  const float* wv = (const float*)d_in[5];
  const float* wp = (const float*)d_in[6];
  float* out = (float*)d_out;

  char* ws = (char*)d_ws;
  float* sx = (float*)(ws);                          // 32KB
  float* sc = (float*)(ws + 32768);                  // 32KB
  ushort* qh = (ushort*)(ws + 65536);                // 8MB  [bh][pos][dh]
  ushort* kh = (ushort*)(ws + 65536 + 8388608);      // 8MB  [bh][key][dh]
  ushort* vt = (ushort*)(ws + 65536 + 16777216);     // 8MB  [bh][dh][pos]
  float* am = (float*)(ws + 65536 + 25165824);       // 16MB [b][c][pos]

  norm_kernel<<<256, 256, 0, stream>>>(x, ctx, sx, sc);
  qkv_kernel<<<dim3(16, 8, 24), 256, 0, stream>>>(x, ctx, gamma, wq, wk, wv,
                                                  sx, sc, qh, kh, vt);
  attn_kernel<<<dim3(4, 64), 512, 0, stream>>>(qh, kh, vt, am);
  proj_kernel<<<dim3(16, 8, 8), 256, 0, stream>>>(am, wp, out);
}

// Round 3
// 68.690 us; speedup vs baseline: 9.3894x; 4.1953x over previous
//
#include <hip/hip_runtime.h>
#include <hip/hip_bf16.h>

// B=8, DIM=512, H=W=32 (1024 pos), NH=8, DH=64, DE=512
// Head-permuted channel index: o' = n*64 + dh  (vs reference o = dh*8 + n)

typedef _Float16 half8v __attribute__((ext_vector_type(8)));
typedef __attribute__((ext_vector_type(4))) float float4v;

__device__ inline ushort f2h(float f) {
  union { _Float16 h; ushort u; } cv;
  cv.h = (_Float16)f;
  return cv.u;
}

__device__ inline void stage16(const void* g, void* l) {
  __builtin_amdgcn_global_load_lds(
      (const __attribute__((address_space(1))) unsigned*)g,
      (__attribute__((address_space(3))) unsigned*)l, 16, 0, 0);
}

// ---------------------------------------------------------------------------
// Kernel 1: fused channel-L2-norm + transpose + f16 convert.
// In : X[b][c=512][pos=1024] fp32
// Out: XT[b][pos][c] f16, S[b][pos] = sqrt(512)/max(||x||,1e-12)
// Block: (b, 32-pos chunk). LDS transpose with 4B-granule swizzle cp^pos.
// ---------------------------------------------------------------------------
__global__ __launch_bounds__(256) void tq_kernel(
    const float* __restrict__ x, const float* __restrict__ ctx,
    ushort* __restrict__ xT, ushort* __restrict__ cT,
    float* __restrict__ sx, float* __restrict__ sc) {
  const int tensor = blockIdx.z;
  const int b = blockIdx.y;
  const int pos0 = blockIdx.x << 5;
  const float* src = tensor ? ctx : x;
  ushort* dstT = tensor ? cT : xT;
  float* dstS = tensor ? sc : sx;
  const int t = threadIdx.x;

  __shared__ ushort tile[32 * 512];  // [posl][c] pairs swizzled, 32KB
  __shared__ float part[32][32];     // [crg][posl]
  unsigned* tile32 = (unsigned*)tile;

  const int pcq = t & 7;   // pos quad
  const int crg = t >> 3;  // 0..31
  float ssq[4] = {0.f, 0.f, 0.f, 0.f};

  const float* srcb = src + ((size_t)b * 512) * 1024 + pos0;
  for (int p = 0; p < 8; ++p) {
    const int cr0 = p * 64 + crg * 2;
    float4 v0 = *(const float4*)&srcb[(size_t)cr0 * 1024 + pcq * 4];
    float4 v1 = *(const float4*)&srcb[(size_t)(cr0 + 1) * 1024 + pcq * 4];
    ssq[0] += v0.x * v0.x + v1.x * v1.x;
    ssq[1] += v0.y * v0.y + v1.y * v1.y;
    ssq[2] += v0.z * v0.z + v1.z * v1.z;
    ssq[3] += v0.w * v0.w + v1.w * v1.w;
    const int cp = cr0 >> 1;
    float e0[4] = {v0.x, v0.y, v0.z, v0.w};
    float e1[4] = {v1.x, v1.y, v1.z, v1.w};
#pragma unroll
    for (int j = 0; j < 4; ++j) {
      const int posl = pcq * 4 + j;
      unsigned pk = (unsigned)f2h(e0[j]) | ((unsigned)f2h(e1[j]) << 16);
      tile32[posl * 256 + (cp ^ posl)] = pk;
    }
  }
#pragma unroll
  for (int j = 0; j < 4; ++j) part[crg][pcq * 4 + j] = ssq[j];
  __syncthreads();
  if (t < 32) {
    float s = 0.f;
#pragma unroll
    for (int g2 = 0; g2 < 32; ++g2) s += part[g2][t];
    dstS[b * 1024 + pos0 + t] = 22.627416997969522f / fmaxf(sqrtf(s), 1e-12f);
  }
  // write-out: 2048 16B chunks
  ushort* ob = dstT + ((size_t)b * 1024 + pos0) * 512;
#pragma unroll
  for (int ii = 0; ii < 8; ++ii) {
    const int m = t + ii * 256;
    const int posl = m >> 6, c16 = m & 63;
    uint4 u;
    u.x = tile32[posl * 256 + ((c16 * 4 + 0) ^ posl)];
    u.y = tile32[posl * 256 + ((c16 * 4 + 1) ^ posl)];
    u.z = tile32[posl * 256 + ((c16 * 4 + 2) ^ posl)];
    u.w = tile32[posl * 256 + ((c16 * 4 + 3) ^ posl)];
    *(uint4*)&ob[(size_t)posl * 512 + c16 * 8] = u;
  }
}

// ---------------------------------------------------------------------------
// Kernel 2: weight prep -> f16.
// m<3 : wf[m][o'][c] = W_m[(o'&63)*8 + (o'>>6)][c] * gamma[c]   (row perm)
// m==3: wf[3][o][c'] = wp[o][(c'&63)*8 + (c'>>6)]               (col perm)
// ---------------------------------------------------------------------------
__global__ __launch_bounds__(256) void wconv_kernel(
    const float* __restrict__ wq, const float* __restrict__ wk,
    const float* __restrict__ wv, const float* __restrict__ wp,
    const float* __restrict__ gamma, ushort* __restrict__ wf) {
  const int m = blockIdx.y;
  const float* W = (m == 0) ? wq : (m == 1) ? wk : (m == 2) ? wv : wp;
  const int r = blockIdx.x * 4 + (threadIdx.x >> 6);
  const int c8 = (threadIdx.x & 63) * 8;
  ushort h[8];
  if (m < 3) {
    const int o = ((r & 63) << 3) + (r >> 6);
    const float* wr_ = &W[(size_t)o * 512 + c8];
#pragma unroll
    for (int j = 0; j < 8; ++j) h[j] = f2h(wr_[j] * gamma[c8 + j]);
  } else {
#pragma unroll
    for (int j = 0; j < 8; ++j) {
      const int cc = c8 + j;
      const int cs = ((cc & 63) << 3) + (cc >> 6);
      h[j] = f2h(W[(size_t)r * 512 + cs]);
    }
  }
  ushort* dst = &wf[((size_t)m * 512 + r) * 512 + c8];
  uint4 u;
  u.x = (unsigned)h[0] | ((unsigned)h[1] << 16);
  u.y = (unsigned)h[2] | ((unsigned)h[3] << 16);
  u.z = (unsigned)h[4] | ((unsigned)h[5] << 16);
  u.w = (unsigned)h[6] | ((unsigned)h[7] << 16);
  *(uint4*)dst = u;
}

// ---------------------------------------------------------------------------
// Kernel 3: QKV projection, f16 MFMA. Per (b, proj): O[pos][o'] tile 128x128.
// A tile: XT rows (pos), B tile: wf rows (o'). K=512 in 8 steps of 64.
// q,k: D[pos][o'] -> [b][pos][o'=n*64+dh]*s[pos]; v: swapped operands ->
// D[o'][pos] -> vt[(b*512+o')][pos]*s[pos].
// ---------------------------------------------------------------------------
__global__ __launch_bounds__(256, 2) void qkv_kernel(
    const ushort* __restrict__ xT, const ushort* __restrict__ cT,
    const ushort* __restrict__ wf, const float* __restrict__ sx,
    const float* __restrict__ sc, ushort* __restrict__ qh,
    ushort* __restrict__ kh, ushort* __restrict__ vt) {
  const int z = blockIdx.z;
  const int proj = z % 3;
  const int b = z / 3;
  const ushort* XT = (proj == 0) ? xT : cT;
  const float* S = (proj == 0) ? sx : sc;
  const ushort* WF = wf + (size_t)proj * 262144;
  const int pos0 = blockIdx.x << 7;
  const int o0 = blockIdx.y << 7;

  __shared__ __align__(16) unsigned char lds[65536];
  unsigned char* Al = lds;
  unsigned char* Bl = lds + 32768;

  const int t = threadIdx.x, w = t >> 6, lane = t & 63;
  const int g = lane >> 4, l15 = lane & 15;
  const int wr = w >> 1, wc = w & 1;
  const int srow_ = lane >> 3;
  const int sslot16 = ((lane & 7) ^ srow_) << 4;

  const unsigned char* Asrc =
      (const unsigned char*)(XT + ((size_t)b * 1024 + pos0) * 512);
  const unsigned char* Bsrc = (const unsigned char*)(WF + (size_t)o0 * 512);

#define QSTAGE(buf, kk)                                                     \
  do {                                                                      \
    _Pragma("unroll") for (int i = 0; i < 4; ++i) {                         \
      const int j = (w << 2) + i;                                           \
      stage16(Asrc + (size_t)((j << 3) + srow_) * 1024 + (kk)*128 + sslot16,\
              Al + (buf)*16384 + (j << 10));                                \
      stage16(Bsrc + (size_t)((j << 3) + srow_) * 1024 + (kk)*128 + sslot16,\
              Bl + (buf)*16384 + (j << 10));                                \
    }                                                                       \
  } while (0)

  float4v acc[4][4];
#pragma unroll
  for (int i = 0; i < 4; ++i)
#pragma unroll
    for (int j2 = 0; j2 < 4; ++j2) acc[i][j2] = (float4v){0.f, 0.f, 0.f, 0.f};

  QSTAGE(0, 0);
  __syncthreads();

  for (int kk = 0; kk < 8; ++kk) {
    const int cur = kk & 1;
    if (kk < 7) QSTAGE(cur ^ 1, kk + 1);
    const unsigned char* At = Al + cur * 16384;
    const unsigned char* Bt = Bl + cur * 16384;
    half8v af[4][2], bf[4][2];
#pragma unroll
    for (int mt = 0; mt < 4; ++mt) {
      const int row = (wr << 6) + (mt << 4) + l15;
      const unsigned char* rb = At + row * 128;
      af[mt][0] = *(const half8v*)(rb + (((g) ^ (row & 7)) << 4));
      af[mt][1] = *(const half8v*)(rb + (((4 + g) ^ (row & 7)) << 4));
    }
#pragma unroll
    for (int nt = 0; nt < 4; ++nt) {
      const int row = (wc << 6) + (nt << 4) + l15;
      const unsigned char* rb = Bt + row * 128;
      bf[nt][0] = *(const half8v*)(rb + (((g) ^ (row & 7)) << 4));
      bf[nt][1] = *(const half8v*)(rb + (((4 + g) ^ (row & 7)) << 4));
    }
    if (proj < 2) {
#pragma unroll
      for (int mt = 0; mt < 4; ++mt)
#pragma unroll
        for (int nt = 0; nt < 4; ++nt) {
          acc[mt][nt] = __builtin_amdgcn_mfma_f32_16x16x32_f16(
              af[mt][0], bf[nt][0], acc[mt][nt], 0, 0, 0);
          acc[mt][nt] = __builtin_amdgcn_mfma_f32_16x16x32_f16(
              af[mt][1], bf[nt][1], acc[mt][nt], 0, 0, 0);
        }
    } else {
#pragma unroll
      for (int mt = 0; mt < 4; ++mt)
#pragma unroll
        for (int nt = 0; nt < 4; ++nt) {
          acc[mt][nt] = __builtin_amdgcn_mfma_f32_16x16x32_f16(
              bf[nt][0], af[mt][0], acc[mt][nt], 0, 0, 0);
          acc[mt][nt] = __builtin_amdgcn_mfma_f32_16x16x32_f16(
              bf[nt][1], af[mt][1], acc[mt][nt], 0, 0, 0);
        }
    }
    __syncthreads();
  }
#undef QSTAGE

  if (proj < 2) {
    ushort* Out = (proj == 0) ? qh : kh;
#pragma unroll
    for (int mt = 0; mt < 4; ++mt) {
      const int posb = pos0 + (wr << 6) + (mt << 4) + (g << 2);
      float4 sv = *(const float4*)&S[b * 1024 + posb];
      float sarr[4] = {sv.x, sv.y, sv.z, sv.w};
#pragma unroll
      for (int nt = 0; nt < 4; ++nt) {
        const int oo = o0 + (wc << 6) + (nt << 4) + l15;
#pragma unroll
        for (int r = 0; r < 3 + 1; ++r) {
          float val = acc[mt][nt][r] * sarr[r];
          Out[((size_t)(b * 1024 + posb + r)) * 512 + oo] = f2h(val);
        }
      }
    }
  } else {
#pragma unroll
    for (int mt = 0; mt < 4; ++mt) {
      const int pos = pos0 + (wr << 6) + (mt << 4) + l15;
      const float sval = S[b * 1024 + pos];
#pragma unroll
      for (int nt = 0; nt < 4; ++nt) {
        const int ob = o0 + (wc << 6) + (nt << 4) + (g << 2);
#pragma unroll
        for (int r = 0; r < 4; ++r) {
          const int oo = ob + r;
          vt[((size_t)(b * 512 + oo)) * 1024 + pos] = f2h(acc[mt][nt][r] * sval);
        }
      }
    }
  }
}

// ---------------------------------------------------------------------------
// Kernel 4: MFMA flash attention (f16), R1 structure.
// q,k: [b][pos][n*64+dh]; vt: [(b*512+o')][pos]; out am: [b][pos][n*64+dh] f16
// ---------------------------------------------------------------------------
__global__ __launch_bounds__(512, 2) void attn_kernel(
    const ushort* __restrict__ qh, const ushort* __restrict__ kh,
    const ushort* __restrict__ vt, ushort* __restrict__ am) {
  __shared__ __align__(16) unsigned char lds[65536];

  const int bh = blockIdx.y;
  const int b = bh >> 3, n = bh & 7;
  const int mbase = blockIdx.x << 8;
  const int t = threadIdx.x;
  const int w = t >> 6;
  const int lane = t & 63;
  const int g = lane >> 4;
  const int l15 = lane & 15;
  const int swz = (l15 & 7) << 4;

  // Q fragments: rows mbase + w*32 + qt*16 + l15
  half8v qf[2][2];
#pragma unroll
  for (int qt = 0; qt < 2; ++qt) {
    const size_t qrow = (size_t)b * 1024 + mbase + w * 32 + qt * 16 + l15;
#pragma unroll
    for (int c = 0; c < 2; ++c)
      qf[qt][c] = *(const half8v*)(qh + qrow * 512 + n * 64 + c * 32 + g * 8);
  }

  float4v o[2][4];
#pragma unroll
  for (int qt = 0; qt < 2; ++qt)
#pragma unroll
    for (int dt = 0; dt < 4; ++dt) o[qt][dt] = (float4v){0.f, 0.f, 0.f, 0.f};
  float rsum[2] = {0.f, 0.f};

  const int srow = (w << 3) + (lane >> 3);
  const int scol = ((lane & 7) ^ (lane >> 3)) << 4;
  const unsigned char* kgb =
      (const unsigned char*)(kh + (size_t)b * 524288 + n * 64) + srow * 1024 +
      scol;
  const unsigned char* vgb =
      (const unsigned char*)(vt + (size_t)(b * 8 + n) * 65536) + srow * 2048 +
      scol;
  unsigned char* Kl = lds;
  unsigned char* Vl = lds + 16384;
  unsigned char* Pl = lds + 32768 + w * 4096;

#define ASTAGE(buf, kt)                                            \
  do {                                                             \
    stage16(kgb + (size_t)(kt)*65536, Kl + (buf)*8192 + w * 1024); \
    stage16(vgb + (size_t)(kt)*128, Vl + (buf)*8192 + w * 1024);   \
  } while (0)

  ASTAGE(0, 0);
  __syncthreads();

  for (int kt = 0; kt < 16; ++kt) {
    const int cur = kt & 1;
    if (kt < 15) ASTAGE(cur ^ 1, kt + 1);

    const unsigned char* Kc = Kl + cur * 8192;
    const unsigned char* Vc = Vl + cur * 8192;

    float4v st[4][2];
#pragma unroll
    for (int ktile = 0; ktile < 4; ++ktile) {
      const unsigned char* krow = Kc + (ktile * 16 + l15) * 128;
      half8v kf0 = *(const half8v*)(krow + ((g * 16) ^ swz));
      half8v kf1 = *(const half8v*)(krow + ((64 + g * 16) ^ swz));
#pragma unroll
      for (int qt = 0; qt < 2; ++qt) {
        float4v a2 = {0.f, 0.f, 0.f, 0.f};
        a2 = __builtin_amdgcn_mfma_f32_16x16x32_f16(kf0, qf[qt][0], a2, 0, 0, 0);
        a2 = __builtin_amdgcn_mfma_f32_16x16x32_f16(kf1, qf[qt][1], a2, 0, 0, 0);
        st[ktile][qt] = a2;
      }
    }

#pragma unroll
    for (int qt = 0; qt < 2; ++qt) {
      unsigned char* prowp = Pl + (qt * 16 + l15) * 128;
#pragma unroll
      for (int ktile = 0; ktile < 4; ++ktile) {
        union { unsigned long long u; ushort s[4]; } pk;
        float4v sv = st[ktile][qt];
#pragma unroll
        for (int r = 0; r < 4; ++r) {
          float p = __expf(sv[r] * 0.125f);
          rsum[qt] += p;
          pk.s[r] = f2h(p);
        }
        *(unsigned long long*)(prowp + ((ktile * 32 + g * 8) ^ swz)) = pk.u;
      }
    }

    half8v pf[2][2];
#pragma unroll
    for (int qt = 0; qt < 2; ++qt)
#pragma unroll
      for (int c = 0; c < 2; ++c)
        pf[qt][c] = *(const half8v*)(Pl + (qt * 16 + l15) * 128 +
                                     ((c * 64 + g * 16) ^ swz));
#pragma unroll
    for (int dt = 0; dt < 4; ++dt) {
      const unsigned char* vrow = Vc + (dt * 16 + l15) * 128;
      half8v vf0 = *(const half8v*)(vrow + ((g * 16) ^ swz));
      half8v vf1 = *(const half8v*)(vrow + ((64 + g * 16) ^ swz));
#pragma unroll
      for (int qt = 0; qt < 2; ++qt) {
        o[qt][dt] = __builtin_amdgcn_mfma_f32_16x16x32_f16(pf[qt][0], vf0,
                                                           o[qt][dt], 0, 0, 0);
        o[qt][dt] = __builtin_amdgcn_mfma_f32_16x16x32_f16(pf[qt][1], vf1,
                                                           o[qt][dt], 0, 0, 0);
      }
    }
    __syncthreads();
  }
#undef ASTAGE

#pragma unroll
  for (int qt = 0; qt < 2; ++qt) {
    float r = rsum[qt];
    r += __shfl_xor(r, 16, 64);
    r += __shfl_xor(r, 32, 64);
    rsum[qt] = 1.0f / r;
  }

#pragma unroll
  for (int qt = 0; qt < 2; ++qt) {
#pragma unroll
    for (int dt = 0; dt < 4; ++dt) {
      float4v ov = o[qt][dt];
      const int d = dt * 16 + l15;
#pragma unroll
      for (int r = 0; r < 4; ++r) {
        float inv = __shfl(rsum[qt], (lane & 48) | (g * 4 + r), 64);
        const int pos = mbase + w * 32 + qt * 16 + g * 4 + r;
        am[((size_t)(b * 1024 + pos)) * 512 + n * 64 + d] = f2h(ov[r] * inv);
      }
    }
  }
}

// ---------------------------------------------------------------------------
// Kernel 5: output projection, f16 MFMA.
// out[b][o][pos] = sum_{c'} wf3[o][c'] * am[b][pos][c']   (fp32 out)
// A tile: wf3 rows (o); B tile: am rows (pos). D[o][pos].
// ---------------------------------------------------------------------------
__global__ __launch_bounds__(256, 2) void proj_kernel(
    const ushort* __restrict__ am, const ushort* __restrict__ wf3,
    float* __restrict__ out) {
  const int b = blockIdx.z;
  const int pos0 = blockIdx.x << 7;
  const int o0 = blockIdx.y << 7;

  __shared__ __align__(16) unsigned char lds[65536];
  unsigned char* Al = lds;
  unsigned char* Bl = lds + 32768;

  const int t = threadIdx.x, w = t >> 6, lane = t & 63;
  const int g = lane >> 4, l15 = lane & 15;
  const int wr = w >> 1, wc = w & 1;
  const int srow_ = lane >> 3;
  const int sslot16 = ((lane & 7) ^ srow_) << 4;

  const unsigned char* Asrc = (const unsigned char*)(wf3 + (size_t)o0 * 512);
  const unsigned char* Bsrc =
      (const unsigned char*)(am + ((size_t)b * 1024 + pos0) * 512);

#define PSTAGE(buf, kk)                                                     \
  do {                                                                      \
    _Pragma("unroll") for (int i = 0; i < 4; ++i) {                         \
      const int j = (w << 2) + i;                                           \
      stage16(Asrc + (size_t)((j << 3) + srow_) * 1024 + (kk)*128 + sslot16,\
              Al + (buf)*16384 + (j << 10));                                \
      stage16(Bsrc + (size_t)((j << 3) + srow_) * 1024 + (kk)*128 + sslot16,\
              Bl + (buf)*16384 + (j << 10));                                \
    }                                                                       \
  } while (0)

  float4v acc[4][4];
#pragma unroll
  for (int i = 0; i < 4; ++i)
#pragma unroll
    for (int j2 = 0; j2 < 4; ++j2) acc[i][j2] = (float4v){0.f, 0.f, 0.f, 0.f};

  PSTAGE(0, 0);
  __syncthreads();

  for (int kk = 0; kk < 8; ++kk) {
    const int cur = kk & 1;
    if (kk < 7) PSTAGE(cur ^ 1, kk + 1);
    const unsigned char* At = Al + cur * 16384;
    const unsigned char* Bt = Bl + cur * 16384;
    half8v af[4][2], bf[4][2];
#pragma unroll
    for (int mt = 0; mt < 4; ++mt) {
      const int row = (wr << 6) + (mt << 4) + l15;
      const unsigned char* rb = At + row * 128;
      af[mt][0] = *(const half8v*)(rb + (((g) ^ (row & 7)) << 4));
      af[mt][1] = *(const half8v*)(rb + (((4 + g) ^ (row & 7)) << 4));
    }
#pragma unroll
    for (int nt = 0; nt < 4; ++nt) {
      const int row = (wc << 6) + (nt << 4) + l15;
      const unsigned char* rb = Bt + row * 128;
      bf[nt][0] = *(const half8v*)(rb + (((g) ^ (row & 7)) << 4));
      bf[nt][1] = *(const half8v*)(rb + (((4 + g) ^ (row & 7)) << 4));
    }
#pragma unroll
    for (int mt = 0; mt < 4; ++mt)
#pragma unroll
      for (int nt = 0; nt < 4; ++nt) {
        acc[mt][nt] = __builtin_amdgcn_mfma_f32_16x16x32_f16(
            af[mt][0], bf[nt][0], acc[mt][nt], 0, 0, 0);
        acc[mt][nt] = __builtin_amdgcn_mfma_f32_16x16x32_f16(
            af[mt][1], bf[nt][1], acc[mt][nt], 0, 0, 0);
      }
    __syncthreads();
  }
#undef PSTAGE

  // D[row=o][col=pos]
#pragma unroll
  for (int mt = 0; mt < 4; ++mt) {
    const int ob = o0 + (wr << 6) + (mt << 4) + (g << 2);
#pragma unroll
    for (int nt = 0; nt < 4; ++nt) {
      const int pos = pos0 + (wc << 6) + (nt << 4) + l15;
#pragma unroll
      for (int r = 0; r < 4; ++r) {
        out[((size_t)(b * 512 + ob + r)) * 1024 + pos] = acc[mt][nt][r];
      }
    }
  }
}

// ---------------------------------------------------------------------------
extern "C" void kernel_launch(void* const* d_in, const int* in_sizes, int n_in,
                              void* d_out, int out_size, void* d_ws,
                              size_t ws_size, hipStream_t stream) {
  const float* x = (const float*)d_in[0];
  const float* ctx = (const float*)d_in[1];
  const float* gamma = (const float*)d_in[2];
  const float* wq = (const float*)d_in[3];
  const float* wk = (const float*)d_in[4];
  const float* wv = (const float*)d_in[5];
  const float* wp = (const float*)d_in[6];
  float* out = (float*)d_out;

  char* ws = (char*)d_ws;
  float* sx = (float*)(ws);                      // 32KB
  float* sc = (float*)(ws + 32768);              // 32KB
  ushort* xT = (ushort*)(ws + 65536);            // 8MB [b][pos][c]
  ushort* cT = (ushort*)(ws + 65536 + 8388608);  // 8MB
  ushort* wf = (ushort*)(ws + 65536 + 16777216); // 2MB (4 x 512x512 f16)
  ushort* qh = (ushort*)(ws + 65536 + 18874368); // 8MB [b][pos][o']
  ushort* kh = (ushort*)(ws + 65536 + 27262976); // 8MB
  ushort* vt = (ushort*)(ws + 65536 + 35651584); // 8MB [(b*512+o')][pos]
  ushort* am = xT;                               // alias: xT dead after qkv

  tq_kernel<<<dim3(32, 8, 2), 256, 0, stream>>>(x, ctx, xT, cT, sx, sc);
  wconv_kernel<<<dim3(128, 4), 256, 0, stream>>>(wq, wk, wv, wp, gamma, wf);
  qkv_kernel<<<dim3(8, 4, 24), 256, 0, stream>>>(xT, cT, wf, sx, sc, qh, kh,
                                                 vt);
  attn_kernel<<<dim3(4, 64), 512, 0, stream>>>(qh, kh, vt, am);
  proj_kernel<<<dim3(8, 4, 8), 256, 0, stream>>>(am, wf + 3 * 262144, out);
}